// Round 1
// baseline (4137.402 us; speedup 1.0000x reference)
//
#include <hip/hip_runtime.h>
#include <math.h>

#define BN 8
#define NA_T 9
#define NPOS 2500
#define FHW 50
#define N_ANCH 22500
#define NG 20
#define PRE 2000
#define POST 300
#define SORT_N 32768
#define TOTAL (BN * N_ANCH)      // 180000
#define HALF_RNG 90000u

// ---------------- device helpers ----------------

__device__ __forceinline__ void anchor_dims(int d, float& w, float& h) {
    // numpy: STRIDE*s*sqrt(r) in float64, cast to float32
    const double scl[3] = {8.0, 16.0, 32.0};
    const double rat[3] = {0.5, 1.0, 2.0};
    double s = 16.0 * scl[d / 3];
    double r = rat[d % 3];
    w = (float)(s * sqrt(r));
    h = (float)(s * sqrt(1.0 / r));
}

__device__ __forceinline__ void anchor_corners(int n, float& x1, float& y1, float& x2, float& y2) {
    int d = n / NPOS, k = n % NPOS;
    float cx = (float)(8 + 16 * (k / FHW));
    float cy = (float)(8 + 16 * (k % FHW));
    float w, h; anchor_dims(d, w, h);
    x1 = cx - 0.5f * w; y1 = cy - 0.5f * h;
    x2 = cx + 0.5f * w; y2 = cy + 0.5f * h;
}

__device__ __forceinline__ float iou_f(float ax1, float ay1, float ax2, float ay2,
                                       float bx1, float by1, float bx2, float by2) {
    float tlx = fmaxf(ax1, bx1), tly = fmaxf(ay1, by1);
    float brx = fminf(ax2, bx2), bry = fminf(ay2, by2);
    float wx = brx - tlx; wx = fmaxf(wx, 0.0f);
    float wy = bry - tly; wy = fmaxf(wy, 0.0f);
    float inter = wx * wy;
    float a1 = (ax2 - ax1) * (ay2 - ay1);
    float a2 = (bx2 - bx1) * (by2 - by1);
    float den = fmaxf(a1 + a2 - inter, 1e-8f);
    return inter / den;
}

__device__ __forceinline__ unsigned int f32_sort_asc(float f) {
    unsigned int u = __float_as_uint(f);
    return (u & 0x80000000u) ? ~u : (u | 0x80000000u);
}

// jax.random.uniform(key(42), (8,22500)) raw bits — ORIGINAL (non-partitionable) threefry path:
// counts = iota(180000), split in half: pair (i, i+90000), output x0 for j<90000 else x1.
#define TF_R(r) { x0 += x1; x1 = ((x1 << r) | (x1 >> (32 - r))); x1 ^= x0; }
__device__ __forceinline__ unsigned int threefry_bits(unsigned int j) {
    unsigned int i = (j < HALF_RNG) ? j : j - HALF_RNG;
    unsigned int x0 = i, x1 = i + HALF_RNG;
    const unsigned int ks0 = 0u, ks1 = 42u, ks2 = 0x1BD11BDAu ^ 0u ^ 42u;
    x0 += ks0; x1 += ks1;
    TF_R(13) TF_R(15) TF_R(26) TF_R(6)
    x0 += ks1; x1 += ks2 + 1u;
    TF_R(17) TF_R(29) TF_R(16) TF_R(24)
    x0 += ks2; x1 += ks0 + 2u;
    TF_R(13) TF_R(15) TF_R(26) TF_R(6)
    x0 += ks0; x1 += ks1 + 3u;
    TF_R(17) TF_R(29) TF_R(16) TF_R(24)
    x0 += ks1; x1 += ks2 + 4u;
    TF_R(13) TF_R(15) TF_R(26) TF_R(6)
    x0 += ks2; x1 += ks0 + 5u;
    return (j < HALF_RNG) ? x0 : x1;
}

__device__ __forceinline__ float smooth_l1(float d) {
    float ad = fabsf(d);
    return (ad < (float)(1.0 / 9.0)) ? (4.5f * d) * d : (ad - (float)(0.5 / 9.0));
}

// ---------------- kernels ----------------

__global__ void k_init(double* acc) {
    if (threadIdx.x < 2) acc[threadIdx.x] = 0.0;
}

__global__ void k_proposals(const float* __restrict__ pred, const float* __restrict__ cls,
                            float* __restrict__ prop, unsigned long long* __restrict__ keys) {
    int t = blockIdx.x * blockDim.x + threadIdx.x;
    if (t >= BN * SORT_N) return;
    int b = t / SORT_N, n = t % SORT_N;
    if (n >= N_ANCH) { keys[t] = ~0ull; return; }
    // anchor (index n interpreted as d*2500+k, per reference anchors array)
    float ax1, ay1, ax2, ay2; anchor_corners(n, ax1, ay1, ax2, ay2);
    float acx = (ax1 + ax2) * 0.5f, acy = (ay1 + ay2) * 0.5f;
    float aw = ax2 - ax1, ah = ay2 - ay1;
    // pd (index n interpreted as (h*50+w)*9 + a, per reference reshape)
    int a = n % NA_T, hw = n / NA_T;
    const float* pb = pred + (size_t)b * 36 * NPOS;
    float dx = pb[(4 * a + 0) * NPOS + hw];
    float dy = pb[(4 * a + 1) * NPOS + hw];
    float dw = pb[(4 * a + 2) * NPOS + hw];
    float dh = pb[(4 * a + 3) * NPOS + hw];
    float px = acx + dx * aw, py = acy + dy * ah;
    float pw = aw * expf(dw), ph = ah * expf(dh);
    float x1 = px - 0.5f * pw, y1 = py - 0.5f * ph;
    float x2 = px + 0.5f * pw, y2 = py + 0.5f * ph;
    x1 = fminf(fmaxf(x1, 0.0f), 799.0f);
    y1 = fminf(fmaxf(y1, 0.0f), 799.0f);
    x2 = fminf(fmaxf(x2, 0.0f), 799.0f);
    y2 = fminf(fmaxf(y2, 0.0f), 799.0f);
    ((float4*)prop)[(size_t)b * N_ANCH + n] = make_float4(x1, y1, x2, y2);
    float score = cls[((size_t)b * 18 + 9 + a) * NPOS + hw];
    unsigned int kd = ~f32_sort_asc(score);   // ascending u64 sort -> descending score, idx tie asc
    keys[t] = ((unsigned long long)kd << 32) | (unsigned int)n;
}

__global__ void __launch_bounds__(1024) k_sort(unsigned long long* __restrict__ keys) {
    unsigned long long* a = keys + (size_t)blockIdx.x * SORT_N;
    for (int k = 2; k <= SORT_N; k <<= 1) {
        for (int j = k >> 1; j > 0; j >>= 1) {
            for (int i = threadIdx.x; i < SORT_N; i += 1024) {
                int l = i ^ j;
                if (l > i) {
                    unsigned long long ai = a[i], al = a[l];
                    bool up = ((i & k) == 0);
                    if ((ai > al) == up) { a[i] = al; a[l] = ai; }
                }
            }
            __syncthreads();
        }
    }
}

__global__ void k_gather(const unsigned long long* __restrict__ keys,
                         const float* __restrict__ prop, float* __restrict__ topb) {
    int t = blockIdx.x * blockDim.x + threadIdx.x;
    if (t >= BN * PRE) return;
    int b = t / PRE, i = t % PRE;
    int idx = (int)(keys[(size_t)b * SORT_N + i] & 0xffffffffu);
    ((float4*)topb)[(size_t)b * PRE + i] = ((const float4*)prop)[(size_t)b * N_ANCH + idx];
}

__global__ void k_nmsmask(const float* __restrict__ topb, unsigned long long* __restrict__ masks) {
    __shared__ float4 boxes[PRE];
    int b = blockIdx.y;
    for (int i = threadIdx.x; i < PRE; i += blockDim.x)
        boxes[i] = ((const float4*)topb)[(size_t)b * PRE + i];
    __syncthreads();
    int i = blockIdx.x * 8 + (threadIdx.x >> 5);
    int chunk = threadIdx.x & 31;
    float4 bi = boxes[i];
    unsigned long long m = 0;
    int j0 = chunk * 64;
    for (int jj = 0; jj < 64; ++jj) {
        int j = j0 + jj;
        if (j < PRE && j > i) {
            float4 bj = boxes[j];
            if (iou_f(bi.x, bi.y, bi.z, bi.w, bj.x, bj.y, bj.z, bj.w) > 0.7f)
                m |= 1ull << jj;
        }
    }
    masks[((size_t)b * PRE + i) * 32 + chunk] = m;
}

__global__ void k_nmsreduce(const unsigned long long* __restrict__ masks,
                            const float* __restrict__ topb, float* __restrict__ out) {
    int b = blockIdx.x;
    int lane = threadIdx.x;  // 64 threads = 1 wave
    __shared__ int keep[POST];
    unsigned long long remv = 0;
    int count = 0;
    for (int i = 0; i < PRE && count < POST; ++i) {
        int c = i >> 6;
        unsigned long long rc = __shfl(remv, c);
        bool sup = (rc >> (i & 63)) & 1ull;
        if (!sup) {
            if (lane == 0 && count < POST) keep[count] = i;
            if (lane < 32) remv |= masks[((size_t)b * PRE + i) * 32 + lane];
            count++;
        }
    }
    __syncthreads();
    for (int s = lane; s < POST; s += 64) {
        float4 v = make_float4(0.f, 0.f, 0.f, 0.f);
        if (s < count) {
            const float* p = topb + ((size_t)b * PRE + keep[s]) * 4;
            v = make_float4(floorf(p[0]), floorf(p[1]), floorf(p[2]), floorf(p[3]));
        }
        ((float4*)out)[(size_t)b * POST + s] = v;
    }
}

__global__ void k_labels(const float* __restrict__ gt, int* __restrict__ labels,
                         int* __restrict__ argmax_b) {
    __shared__ float4 g[NG];
    int b = blockIdx.y;
    if (threadIdx.x < NG) g[threadIdx.x] = ((const float4*)gt)[b * NG + threadIdx.x];
    __syncthreads();
    int n = blockIdx.x * blockDim.x + threadIdx.x;
    if (n >= N_ANCH) return;
    float ax1, ay1, ax2, ay2; anchor_corners(n, ax1, ay1, ax2, ay2);
    float best = -1.0f; int bi = 0;
    for (int gi = 0; gi < NG; ++gi) {
        float4 G = g[gi];
        float v = iou_f(G.x, G.y, G.z, G.w, ax1, ay1, ax2, ay2);
        if (v > best) { best = v; bi = gi; }  // first-max
    }
    int lab = -1;
    if (best < 0.3f) lab = 0;
    if (best >= 0.7f) lab = 1;
    labels[b * N_ANCH + n] = lab;
    argmax_b[b * N_ANCH + n] = bi;
}

__global__ void k_gtbest(const float* __restrict__ gt, int* __restrict__ gt_best) {
    int b = blockIdx.x / NG, gi = blockIdx.x % NG;
    float4 G = ((const float4*)gt)[b * NG + gi];
    float best = -1.0f; int bidx = N_ANCH;
    for (int n = threadIdx.x; n < N_ANCH; n += blockDim.x) {
        float ax1, ay1, ax2, ay2; anchor_corners(n, ax1, ay1, ax2, ay2);
        float v = iou_f(G.x, G.y, G.z, G.w, ax1, ay1, ax2, ay2);
        if (v > best) { best = v; bidx = n; }  // ascending n per thread -> first-max
    }
    __shared__ float sv[256]; __shared__ int si[256];
    sv[threadIdx.x] = best; si[threadIdx.x] = bidx;
    __syncthreads();
    for (int s = 128; s > 0; s >>= 1) {
        if (threadIdx.x < s) {
            float v2 = sv[threadIdx.x + s]; int i2 = si[threadIdx.x + s];
            if (v2 > sv[threadIdx.x] || (v2 == sv[threadIdx.x] && i2 < si[threadIdx.x])) {
                sv[threadIdx.x] = v2; si[threadIdx.x] = i2;
            }
        }
        __syncthreads();
    }
    if (threadIdx.x == 0) gt_best[blockIdx.x] = si[0];
}

__global__ void k_gtapply(const int* __restrict__ gt_best, int* __restrict__ labels) {
    int t = threadIdx.x;
    if (t < BN * NG) {
        int b = t / NG;
        labels[b * N_ANCH + gt_best[t]] = 1;
    }
}

__global__ void k_inside(int* __restrict__ labels) {
    int t = blockIdx.x * blockDim.x + threadIdx.x;
    if (t >= TOTAL) return;
    int n = t % N_ANCH;
    float x1, y1, x2, y2; anchor_corners(n, x1, y1, x2, y2);
    if (x1 >= 0.0f && y1 >= 0.0f && x2 <= 800.0f && y2 <= 800.0f) labels[t] = -1;
}

__global__ void k_count(const int* __restrict__ labels, int* __restrict__ cnt_pos,
                        int* __restrict__ cnt_neg) {
    int b = blockIdx.x;
    int cp = 0, cn = 0;
    for (int n = threadIdx.x; n < N_ANCH; n += blockDim.x) {
        int l = labels[b * N_ANCH + n];
        cp += (l == 1); cn += (l == 0);
    }
    __shared__ int sp[256], sn[256];
    sp[threadIdx.x] = cp; sn[threadIdx.x] = cn;
    __syncthreads();
    for (int s = 128; s > 0; s >>= 1) {
        if (threadIdx.x < s) { sp[threadIdx.x] += sp[threadIdx.x + s]; sn[threadIdx.x] += sn[threadIdx.x + s]; }
        __syncthreads();
    }
    if (threadIdx.x == 0) { cnt_pos[b] = sp[0]; cnt_neg[b] = sn[0]; }
}

__global__ void k_buildkeys(const int* __restrict__ labels, unsigned long long* __restrict__ keys,
                            int* __restrict__ final_labels, int target, int init_final) {
    int t = blockIdx.x * blockDim.x + threadIdx.x;
    if (t >= BN * SORT_N) return;
    int b = t / SORT_N, n = t % SORT_N;
    if (n >= N_ANCH) { keys[t] = ~0ull; return; }
    int gi = b * N_ANCH + n;
    if (init_final) final_labels[gi] = -1;
    unsigned long long key = ~0ull;
    if (labels[gi] == target) {
        unsigned int mant = threefry_bits((unsigned int)gi) >> 9;  // r ordering == mantissa ordering
        key = ((unsigned long long)mant << 32) | (unsigned int)n;
    }
    keys[t] = key;
}

__global__ void k_mark(const unsigned long long* __restrict__ keys, const int* __restrict__ cnt_pos,
                       const int* __restrict__ cnt_neg, int* __restrict__ final_labels, int is_pos) {
    int b = blockIdx.x, t = threadIdx.x;  // 256 threads
    int np = min(cnt_pos[b], 128);
    int lim, val;
    if (is_pos) { lim = np; val = 1; }
    else { lim = min(cnt_neg[b], 256 - np); val = 0; }
    if (t < lim) {
        int idx = (int)(keys[(size_t)b * SORT_N + t] & 0xffffffffu);
        final_labels[b * N_ANCH + idx] = val;
    }
}

__global__ void k_loss(const float* __restrict__ pred, const float* __restrict__ cls,
                       const float* __restrict__ gt, const int* __restrict__ final_labels,
                       const int* __restrict__ argmax_b, double* __restrict__ acc) {
    int t = blockIdx.x * blockDim.x + threadIdx.x;
    if (t >= TOTAL) return;
    int lab = final_labels[t];
    if (lab < 0) return;
    int b = t / N_ANCH, n = t % N_ANCH;
    int a = n % NA_T, hw = n / NA_T;
    // cls2 pair = channels (2a, 2a+1)
    float l0 = cls[((size_t)b * 18 + 2 * a + 0) * NPOS + hw];
    float l1 = cls[((size_t)b * 18 + 2 * a + 1) * NPOS + hw];
    float m = fmaxf(l0, l1);
    float s0 = l0 - m, s1 = l1 - m;
    float lse = logf(expf(s0) + expf(s1));
    float logp = (lab ? s1 : s0) - lse;
    atomicAdd(&acc[0], (double)(-logp));
    if (lab == 1) {
        const float* pb = pred + (size_t)b * 36 * NPOS;
        float dx = pb[(4 * a + 0) * NPOS + hw];
        float dy = pb[(4 * a + 1) * NPOS + hw];
        float dw = pb[(4 * a + 2) * NPOS + hw];
        float dh = pb[(4 * a + 3) * NPOS + hw];
        float ax1, ay1, ax2, ay2; anchor_corners(n, ax1, ay1, ax2, ay2);
        float acx = (ax1 + ax2) * 0.5f, acy = (ay1 + ay2) * 0.5f;
        float aw = ax2 - ax1, ah = ay2 - ay1;
        float4 G = ((const float4*)gt)[b * NG + argmax_b[t]];
        float gcx = (G.x + G.z) * 0.5f, gcy = (G.y + G.w) * 0.5f;
        float gw = G.z - G.x, gh = G.w - G.y;
        float t0 = (gcx - acx) / aw, t1 = (gcy - acy) / ah;
        float t2 = logf(gw / aw), t3 = logf(gh / ah);
        float s = smooth_l1(dx - t0) + smooth_l1(dy - t1) + smooth_l1(dw - t2) + smooth_l1(dh - t3);
        atomicAdd(&acc[1], (double)s);
    }
}

__global__ void k_final(const double* __restrict__ acc, const int* __restrict__ cnt_pos,
                        const int* __restrict__ cnt_neg, float* __restrict__ out) {
    if (threadIdx.x != 0 || blockIdx.x != 0) return;
    int total = 0, count0 = 0;
    for (int b = 0; b < BN; ++b) {
        int np = min(cnt_pos[b], 128);
        int nn = min(cnt_neg[b], 256 - np);
        total += np + nn;
        if (b == 0) count0 = np + nn;
    }
    out[BN * POST * 4 + 0] = (float)(acc[1] / (double)max(count0, 1));  // bbox_loss
    out[BN * POST * 4 + 1] = (float)(acc[0] / (double)max(total, 1));   // cls_loss
}

// ---------------- launch ----------------

extern "C" void kernel_launch(void* const* d_in, const int* in_sizes, int n_in,
                              void* d_out, int out_size, void* d_ws, size_t ws_size,
                              hipStream_t stream) {
    (void)in_sizes; (void)n_in; (void)out_size; (void)ws_size;
    const float* pred = (const float*)d_in[0];   // (8,36,50,50)
    const float* cls  = (const float*)d_in[1];   // (8,18,50,50)
    const float* gt   = (const float*)d_in[2];   // (8,20,4)
    float* out = (float*)d_out;                  // 9600 boxes + 2 losses

    char* w = (char*)d_ws;
    size_t off = 0;
    auto take = [&](size_t bytes) { void* p = w + off; off += (bytes + 255) & ~(size_t)255; return p; };
    float* prop                = (float*)take((size_t)BN * N_ANCH * 4 * 4);          // 2.88 MB
    unsigned long long* keys   = (unsigned long long*)take((size_t)BN * SORT_N * 8); // 2.10 MB
    float* topb                = (float*)take((size_t)BN * PRE * 4 * 4);             // 256 KB
    unsigned long long* masks  = (unsigned long long*)take((size_t)BN * PRE * 32 * 8); // 4.10 MB
    int* labels                = (int*)take((size_t)TOTAL * 4);                      // 720 KB
    int* final_labels          = (int*)take((size_t)TOTAL * 4);                      // 720 KB
    int* argmax_b              = (int*)take((size_t)TOTAL * 4);                      // 720 KB
    int* gt_best               = (int*)take((size_t)BN * NG * 4);
    int* cnt_pos               = (int*)take(BN * 4);
    int* cnt_neg               = (int*)take(BN * 4);
    double* acc                = (double*)take(2 * 8);

    k_init<<<1, 64, 0, stream>>>(acc);
    k_proposals<<<(BN * SORT_N + 255) / 256, 256, 0, stream>>>(pred, cls, prop, keys);
    k_sort<<<BN, 1024, 0, stream>>>(keys);
    k_gather<<<(BN * PRE + 255) / 256, 256, 0, stream>>>(keys, prop, topb);
    k_nmsmask<<<dim3(PRE / 8, BN), 256, 0, stream>>>(topb, masks);
    k_nmsreduce<<<BN, 64, 0, stream>>>(masks, topb, out);
    k_labels<<<dim3((N_ANCH + 255) / 256, BN), 256, 0, stream>>>(gt, labels, argmax_b);
    k_gtbest<<<BN * NG, 256, 0, stream>>>(gt, gt_best);
    k_gtapply<<<1, 256, 0, stream>>>(gt_best, labels);
    k_inside<<<(TOTAL + 255) / 256, 256, 0, stream>>>(labels);
    k_count<<<BN, 256, 0, stream>>>(labels, cnt_pos, cnt_neg);
    // positives: init final labels to -1, sort pos keys, mark first n_pos
    k_buildkeys<<<(BN * SORT_N + 255) / 256, 256, 0, stream>>>(labels, keys, final_labels, 1, 1);
    k_sort<<<BN, 1024, 0, stream>>>(keys);
    k_mark<<<BN, 256, 0, stream>>>(keys, cnt_pos, cnt_neg, final_labels, 1);
    // negatives
    k_buildkeys<<<(BN * SORT_N + 255) / 256, 256, 0, stream>>>(labels, keys, final_labels, 0, 0);
    k_sort<<<BN, 1024, 0, stream>>>(keys);
    k_mark<<<BN, 256, 0, stream>>>(keys, cnt_pos, cnt_neg, final_labels, 0);
    k_loss<<<(TOTAL + 255) / 256, 256, 0, stream>>>(pred, cls, gt, final_labels, argmax_b, acc);
    k_final<<<1, 64, 0, stream>>>(acc, cnt_pos, cnt_neg, out);
}

// Round 2
// 556.692 us; speedup vs baseline: 7.4321x; 7.4321x over previous
//
#include <hip/hip_runtime.h>
#include <math.h>

#define BN 8
#define NA_T 9
#define NPOS 2500
#define FHW 50
#define N_ANCH 22500
#define NG 20
#define PRE 2000
#define POST 300
#define TOTAL (BN * N_ANCH)      // 180000
#define HALF_RNG 90000u

// ---------------- device helpers ----------------

__device__ __forceinline__ void anchor_dims(int d, float& w, float& h) {
    const double scl[3] = {8.0, 16.0, 32.0};
    const double rat[3] = {0.5, 1.0, 2.0};
    double s = 16.0 * scl[d / 3];
    double r = rat[d % 3];
    w = (float)(s * sqrt(r));
    h = (float)(s * sqrt(1.0 / r));
}

__device__ __forceinline__ void anchor_corners(int n, float& x1, float& y1, float& x2, float& y2) {
    int d = n / NPOS, k = n % NPOS;
    float cx = (float)(8 + 16 * (k / FHW));
    float cy = (float)(8 + 16 * (k % FHW));
    float w, h; anchor_dims(d, w, h);
    x1 = cx - 0.5f * w; y1 = cy - 0.5f * h;
    x2 = cx + 0.5f * w; y2 = cy + 0.5f * h;
}

__device__ __forceinline__ float iou_f(float ax1, float ay1, float ax2, float ay2,
                                       float bx1, float by1, float bx2, float by2) {
    float tlx = fmaxf(ax1, bx1), tly = fmaxf(ay1, by1);
    float brx = fminf(ax2, bx2), bry = fminf(ay2, by2);
    float wx = fmaxf(brx - tlx, 0.0f);
    float wy = fmaxf(bry - tly, 0.0f);
    float inter = wx * wy;
    float a1 = (ax2 - ax1) * (ay2 - ay1);
    float a2 = (bx2 - bx1) * (by2 - by1);
    float den = fmaxf(a1 + a2 - inter, 1e-8f);
    return inter / den;
}

__device__ __forceinline__ unsigned int f32_sort_asc(float f) {
    unsigned int u = __float_as_uint(f);
    return (u & 0x80000000u) ? ~u : (u | 0x80000000u);
}

#define TF_R(r) { x0 += x1; x1 = ((x1 << r) | (x1 >> (32 - r))); x1 ^= x0; }
__device__ __forceinline__ unsigned int threefry_bits(unsigned int j) {
    unsigned int i = (j < HALF_RNG) ? j : j - HALF_RNG;
    unsigned int x0 = i, x1 = i + HALF_RNG;
    const unsigned int ks0 = 0u, ks1 = 42u, ks2 = 0x1BD11BDAu ^ 0u ^ 42u;
    x0 += ks0; x1 += ks1;
    TF_R(13) TF_R(15) TF_R(26) TF_R(6)
    x0 += ks1; x1 += ks2 + 1u;
    TF_R(17) TF_R(29) TF_R(16) TF_R(24)
    x0 += ks2; x1 += ks0 + 2u;
    TF_R(13) TF_R(15) TF_R(26) TF_R(6)
    x0 += ks0; x1 += ks1 + 3u;
    TF_R(17) TF_R(29) TF_R(16) TF_R(24)
    x0 += ks1; x1 += ks2 + 4u;
    TF_R(13) TF_R(15) TF_R(26) TF_R(6)
    x0 += ks2; x1 += ks0 + 5u;
    return (j < HALF_RNG) ? x0 : x1;
}

__device__ __forceinline__ float smooth_l1(float d) {
    float ad = fabsf(d);
    return (ad < (float)(1.0 / 9.0)) ? (4.5f * d) * d : (ad - (float)(0.5 / 9.0));
}

// Exact rank-`target` (1-indexed) smallest key among active register-held keys,
// block-wide. Keys must be unique. All threads must call with uniform `target`>=1.
__device__ unsigned long long radix_select_block(
    const unsigned long long* mykeys, unsigned int amask, int cnt,
    unsigned int target, unsigned int* hist,
    unsigned long long* s_prefix, unsigned int* s_rem) {
    unsigned long long prefix = 0;
    unsigned int remaining = target;
    for (int shift = 56; shift >= 0; shift -= 8) {
        unsigned long long hm = (shift + 8 >= 64) ? 0ull : (~0ull << (shift + 8));
        for (int i = threadIdx.x; i < 256; i += blockDim.x) hist[i] = 0;
        __syncthreads();
        for (int c = 0; c < cnt; ++c) {
            if ((amask >> c) & 1u) {
                unsigned long long kk = mykeys[c];
                if ((kk & hm) == (prefix & hm))
                    atomicAdd(&hist[(unsigned int)((kk >> shift) & 255)], 1u);
            }
        }
        __syncthreads();
        if (threadIdx.x == 0) {
            unsigned int cum = 0; int digit = 255;
            for (int d = 0; d < 256; ++d) {
                unsigned int h = hist[d];
                if (cum + h >= remaining) { digit = d; break; }
                cum += h;
            }
            *s_prefix = prefix | ((unsigned long long)digit << shift);
            *s_rem = remaining - cum;
        }
        __syncthreads();
        prefix = *s_prefix;
        remaining = *s_rem;
        __syncthreads();
    }
    return prefix;
}

// ---------------- kernels ----------------

__global__ void k_init(double* acc) {
    if (threadIdx.x < 2) acc[threadIdx.x] = 0.0;
}

__global__ void k_proposals(const float* __restrict__ pred, const float* __restrict__ cls,
                            float* __restrict__ prop, unsigned long long* __restrict__ keys) {
    int t = blockIdx.x * blockDim.x + threadIdx.x;
    if (t >= TOTAL) return;
    int b = t / N_ANCH, n = t % N_ANCH;
    float ax1, ay1, ax2, ay2; anchor_corners(n, ax1, ay1, ax2, ay2);
    float acx = (ax1 + ax2) * 0.5f, acy = (ay1 + ay2) * 0.5f;
    float aw = ax2 - ax1, ah = ay2 - ay1;
    int a = n % NA_T, hw = n / NA_T;
    const float* pb = pred + (size_t)b * 36 * NPOS;
    float dx = pb[(4 * a + 0) * NPOS + hw];
    float dy = pb[(4 * a + 1) * NPOS + hw];
    float dw = pb[(4 * a + 2) * NPOS + hw];
    float dh = pb[(4 * a + 3) * NPOS + hw];
    float px = acx + dx * aw, py = acy + dy * ah;
    float pw = aw * expf(dw), ph = ah * expf(dh);
    float x1 = px - 0.5f * pw, y1 = py - 0.5f * ph;
    float x2 = px + 0.5f * pw, y2 = py + 0.5f * ph;
    x1 = fminf(fmaxf(x1, 0.0f), 799.0f);
    y1 = fminf(fmaxf(y1, 0.0f), 799.0f);
    x2 = fminf(fmaxf(x2, 0.0f), 799.0f);
    y2 = fminf(fmaxf(y2, 0.0f), 799.0f);
    ((float4*)prop)[(size_t)b * N_ANCH + n] = make_float4(x1, y1, x2, y2);
    float score = cls[((size_t)b * 18 + 9 + a) * NPOS + hw];
    unsigned int kd = ~f32_sort_asc(score);   // ascending u64 -> descending score, idx ties asc
    keys[t] = ((unsigned long long)kd << 32) | (unsigned int)n;
}

// top-2000 (exact lax.top_k semantics) via radix-threshold select + 2048 LDS bitonic sort
__global__ void __launch_bounds__(1024) k_topk(const unsigned long long* __restrict__ keys,
                                               const float* __restrict__ prop,
                                               float* __restrict__ topb) {
    int b = blockIdx.x;
    const unsigned long long* kb = keys + (size_t)b * N_ANCH;
    unsigned long long mykeys[22];
    int cnt = 0;
    for (int n = threadIdx.x; n < N_ANCH; n += 1024) mykeys[cnt++] = kb[n];
    unsigned int amask = (1u << cnt) - 1u;

    __shared__ unsigned int hist[256];
    __shared__ unsigned long long s_prefix;
    __shared__ unsigned int s_rem;
    unsigned long long T = radix_select_block(mykeys, amask, cnt, PRE, hist, &s_prefix, &s_rem);

    __shared__ unsigned long long sk[2048];
    __shared__ unsigned int s_cnt;
    if (threadIdx.x == 0) s_cnt = 0;
    for (int i = threadIdx.x; i < 2048; i += 1024) sk[i] = ~0ull;
    __syncthreads();
    for (int c = 0; c < cnt; ++c)
        if (mykeys[c] <= T) { unsigned int p = atomicAdd(&s_cnt, 1u); sk[p] = mykeys[c]; }
    __syncthreads();
    // bitonic sort 2048 in LDS
    for (int k = 2; k <= 2048; k <<= 1) {
        for (int j = k >> 1; j > 0; j >>= 1) {
            for (int i = threadIdx.x; i < 2048; i += 1024) {
                int l = i ^ j;
                if (l > i) {
                    unsigned long long ai = sk[i], al = sk[l];
                    bool up = ((i & k) == 0);
                    if ((ai > al) == up) { sk[i] = al; sk[l] = ai; }
                }
            }
            __syncthreads();
        }
    }
    // gather boxes of sorted top-2000
    for (int i = threadIdx.x; i < PRE; i += 1024) {
        int idx = (int)(sk[i] & 0xffffffffu);
        ((float4*)topb)[(size_t)b * PRE + i] = ((const float4*)prop)[(size_t)b * N_ANCH + idx];
    }
}

__global__ void k_nmsmask(const float* __restrict__ topb, unsigned long long* __restrict__ masks) {
    __shared__ float4 boxes[PRE];
    int b = blockIdx.y;
    for (int i = threadIdx.x; i < PRE; i += blockDim.x)
        boxes[i] = ((const float4*)topb)[(size_t)b * PRE + i];
    __syncthreads();
    int i = blockIdx.x * 8 + (threadIdx.x >> 5);
    int chunk = threadIdx.x & 31;
    float4 bi = boxes[i];
    unsigned long long m = 0;
    int j0 = chunk * 64;
    for (int jj = 0; jj < 64; ++jj) {
        int j = j0 + jj;
        if (j < PRE && j > i) {
            float4 bj = boxes[j];
            if (iou_f(bi.x, bi.y, bi.z, bi.w, bj.x, bj.y, bj.z, bj.w) > 0.7f)
                m |= 1ull << jj;
        }
    }
    masks[((size_t)b * PRE + i) * 32 + chunk] = m;
}

__global__ void k_nmsreduce(const unsigned long long* __restrict__ masks,
                            const float* __restrict__ topb, float* __restrict__ out) {
    int b = blockIdx.x;
    int lane = threadIdx.x;  // 64 threads = 1 wave
    __shared__ int keep[POST];
    unsigned long long remv = 0;
    int count = 0;
    for (int i = 0; i < PRE && count < POST; ++i) {
        int c = i >> 6;
        unsigned long long rc = __shfl(remv, c);
        bool sup = (rc >> (i & 63)) & 1ull;
        if (!sup) {
            if (lane == 0 && count < POST) keep[count] = i;
            if (lane < 32) remv |= masks[((size_t)b * PRE + i) * 32 + lane];
            count++;
        }
    }
    __syncthreads();
    for (int s = lane; s < POST; s += 64) {
        float4 v = make_float4(0.f, 0.f, 0.f, 0.f);
        if (s < count) {
            const float* p = topb + ((size_t)b * PRE + keep[s]) * 4;
            v = make_float4(floorf(p[0]), floorf(p[1]), floorf(p[2]), floorf(p[3]));
        }
        ((float4*)out)[(size_t)b * POST + s] = v;
    }
}

__global__ void k_labels(const float* __restrict__ gt, int* __restrict__ labels,
                         int* __restrict__ argmax_b) {
    __shared__ float4 g[NG];
    int b = blockIdx.y;
    if (threadIdx.x < NG) g[threadIdx.x] = ((const float4*)gt)[b * NG + threadIdx.x];
    __syncthreads();
    int n = blockIdx.x * blockDim.x + threadIdx.x;
    if (n >= N_ANCH) return;
    float ax1, ay1, ax2, ay2; anchor_corners(n, ax1, ay1, ax2, ay2);
    float best = -1.0f; int bi = 0;
    for (int gi = 0; gi < NG; ++gi) {
        float4 G = g[gi];
        float v = iou_f(G.x, G.y, G.z, G.w, ax1, ay1, ax2, ay2);
        if (v > best) { best = v; bi = gi; }  // first-max
    }
    int lab = -1;
    if (best < 0.3f) lab = 0;
    if (best >= 0.7f) lab = 1;
    labels[b * N_ANCH + n] = lab;
    argmax_b[b * N_ANCH + n] = bi;
}

__global__ void k_gtbest(const float* __restrict__ gt, int* __restrict__ gt_best) {
    int b = blockIdx.x / NG, gi = blockIdx.x % NG;
    float4 G = ((const float4*)gt)[b * NG + gi];
    float best = -1.0f; int bidx = N_ANCH;
    for (int n = threadIdx.x; n < N_ANCH; n += blockDim.x) {
        float ax1, ay1, ax2, ay2; anchor_corners(n, ax1, ay1, ax2, ay2);
        float v = iou_f(G.x, G.y, G.z, G.w, ax1, ay1, ax2, ay2);
        if (v > best) { best = v; bidx = n; }
    }
    __shared__ float sv[256]; __shared__ int si[256];
    sv[threadIdx.x] = best; si[threadIdx.x] = bidx;
    __syncthreads();
    for (int s = 128; s > 0; s >>= 1) {
        if (threadIdx.x < s) {
            float v2 = sv[threadIdx.x + s]; int i2 = si[threadIdx.x + s];
            if (v2 > sv[threadIdx.x] || (v2 == sv[threadIdx.x] && i2 < si[threadIdx.x])) {
                sv[threadIdx.x] = v2; si[threadIdx.x] = i2;
            }
        }
        __syncthreads();
    }
    if (threadIdx.x == 0) gt_best[blockIdx.x] = si[0];
}

__global__ void k_gtapply(const int* __restrict__ gt_best, int* __restrict__ labels) {
    int t = threadIdx.x;
    if (t < BN * NG) {
        int b = t / NG;
        labels[b * N_ANCH + gt_best[t]] = 1;
    }
}

// fused: inside-override + pos/neg count + exact random subsample (threefry) -> final labels
__global__ void __launch_bounds__(1024) k_sample(const int* __restrict__ labels,
                                                 int* __restrict__ final_labels,
                                                 int* __restrict__ cnt_out) {
    int b = blockIdx.x;
    unsigned long long mykeys[22];
    unsigned int posmask = 0, negmask = 0;
    int cnt = 0, cp = 0, cn = 0;
    for (int n = threadIdx.x; n < N_ANCH; n += 1024) {
        int l = labels[b * N_ANCH + n];
        float x1, y1, x2, y2; anchor_corners(n, x1, y1, x2, y2);
        if (x1 >= 0.0f && y1 >= 0.0f && x2 <= 800.0f && y2 <= 800.0f) l = -1;  // INSIDE_IDX -> -1
        unsigned int mant = threefry_bits((unsigned int)(b * N_ANCH + n)) >> 9;
        mykeys[cnt] = ((unsigned long long)mant << 32) | (unsigned int)n;
        if (l == 1) { posmask |= 1u << cnt; cp++; }
        else if (l == 0) { negmask |= 1u << cnt; cn++; }
        cnt++;
    }
    __shared__ int red[1024];
    red[threadIdx.x] = cp; __syncthreads();
    for (int s = 512; s > 0; s >>= 1) { if (threadIdx.x < s) red[threadIdx.x] += red[threadIdx.x + s]; __syncthreads(); }
    int cpt = red[0]; __syncthreads();
    red[threadIdx.x] = cn; __syncthreads();
    for (int s = 512; s > 0; s >>= 1) { if (threadIdx.x < s) red[threadIdx.x] += red[threadIdx.x + s]; __syncthreads(); }
    int cnt_tot = red[0]; __syncthreads();
    int np = min(cpt, 128);
    int nn = min(cnt_tot, 256 - np);

    __shared__ unsigned int hist[256];
    __shared__ unsigned long long s_prefix;
    __shared__ unsigned int s_rem;
    unsigned long long Tpos = 0, Tneg = 0;
    bool haspos = (np > 0), hasneg = (nn > 0);
    if (haspos) Tpos = radix_select_block(mykeys, posmask, cnt, (unsigned int)np, hist, &s_prefix, &s_rem);
    __syncthreads();
    if (hasneg) Tneg = radix_select_block(mykeys, negmask, cnt, (unsigned int)nn, hist, &s_prefix, &s_rem);

    int c = 0;
    for (int n = threadIdx.x; n < N_ANCH; n += 1024) {
        int outv = -1;
        if ((posmask >> c) & 1u) { if (haspos && mykeys[c] <= Tpos) outv = 1; }
        else if ((negmask >> c) & 1u) { if (hasneg && mykeys[c] <= Tneg) outv = 0; }
        final_labels[b * N_ANCH + n] = outv;
        c++;
    }
    if (threadIdx.x == 0) cnt_out[b] = np + nn;
}

__global__ void k_loss(const float* __restrict__ pred, const float* __restrict__ cls,
                       const float* __restrict__ gt, const int* __restrict__ final_labels,
                       const int* __restrict__ argmax_b, double* __restrict__ acc) {
    int t = blockIdx.x * blockDim.x + threadIdx.x;
    if (t >= TOTAL) return;
    int lab = final_labels[t];
    if (lab < 0) return;
    int b = t / N_ANCH, n = t % N_ANCH;
    int a = n % NA_T, hw = n / NA_T;
    float l0 = cls[((size_t)b * 18 + 2 * a + 0) * NPOS + hw];
    float l1 = cls[((size_t)b * 18 + 2 * a + 1) * NPOS + hw];
    float m = fmaxf(l0, l1);
    float s0 = l0 - m, s1 = l1 - m;
    float lse = logf(expf(s0) + expf(s1));
    float logp = (lab ? s1 : s0) - lse;
    atomicAdd(&acc[0], (double)(-logp));
    if (lab == 1) {
        const float* pb = pred + (size_t)b * 36 * NPOS;
        float dx = pb[(4 * a + 0) * NPOS + hw];
        float dy = pb[(4 * a + 1) * NPOS + hw];
        float dw = pb[(4 * a + 2) * NPOS + hw];
        float dh = pb[(4 * a + 3) * NPOS + hw];
        float ax1, ay1, ax2, ay2; anchor_corners(n, ax1, ay1, ax2, ay2);
        float acx = (ax1 + ax2) * 0.5f, acy = (ay1 + ay2) * 0.5f;
        float aw = ax2 - ax1, ah = ay2 - ay1;
        float4 G = ((const float4*)gt)[b * NG + argmax_b[t]];
        float gcx = (G.x + G.z) * 0.5f, gcy = (G.y + G.w) * 0.5f;
        float gw = G.z - G.x, gh = G.w - G.y;
        float t0 = (gcx - acx) / aw, t1 = (gcy - acy) / ah;
        float t2 = logf(gw / aw), t3 = logf(gh / ah);
        float s = smooth_l1(dx - t0) + smooth_l1(dy - t1) + smooth_l1(dw - t2) + smooth_l1(dh - t3);
        atomicAdd(&acc[1], (double)s);
    }
}

__global__ void k_final(const double* __restrict__ acc, const int* __restrict__ cnt_out,
                        float* __restrict__ out) {
    if (threadIdx.x != 0 || blockIdx.x != 0) return;
    int total = 0, count0 = 0;
    for (int b = 0; b < BN; ++b) {
        total += cnt_out[b];
        if (b == 0) count0 = cnt_out[b];
    }
    out[BN * POST * 4 + 0] = (float)(acc[1] / (double)max(count0, 1));  // bbox_loss
    out[BN * POST * 4 + 1] = (float)(acc[0] / (double)max(total, 1));   // cls_loss
}

// ---------------- launch ----------------

extern "C" void kernel_launch(void* const* d_in, const int* in_sizes, int n_in,
                              void* d_out, int out_size, void* d_ws, size_t ws_size,
                              hipStream_t stream) {
    (void)in_sizes; (void)n_in; (void)out_size; (void)ws_size;
    const float* pred = (const float*)d_in[0];   // (8,36,50,50)
    const float* cls  = (const float*)d_in[1];   // (8,18,50,50)
    const float* gt   = (const float*)d_in[2];   // (8,20,4)
    float* out = (float*)d_out;                  // 9600 boxes + 2 losses

    char* w = (char*)d_ws;
    size_t off = 0;
    auto take = [&](size_t bytes) { void* p = w + off; off += (bytes + 255) & ~(size_t)255; return p; };
    float* prop                = (float*)take((size_t)BN * N_ANCH * 4 * 4);            // 2.88 MB
    unsigned long long* keys   = (unsigned long long*)take((size_t)TOTAL * 8);         // 1.44 MB
    float* topb                = (float*)take((size_t)BN * PRE * 4 * 4);               // 256 KB
    unsigned long long* masks  = (unsigned long long*)take((size_t)BN * PRE * 32 * 8); // 4.10 MB
    int* labels                = (int*)take((size_t)TOTAL * 4);                        // 720 KB
    int* final_labels          = (int*)take((size_t)TOTAL * 4);                        // 720 KB
    int* argmax_b              = (int*)take((size_t)TOTAL * 4);                        // 720 KB
    int* gt_best               = (int*)take((size_t)BN * NG * 4);
    int* cnt_out               = (int*)take(BN * 4);
    double* acc                = (double*)take(2 * 8);

    k_init<<<1, 64, 0, stream>>>(acc);
    k_proposals<<<(TOTAL + 255) / 256, 256, 0, stream>>>(pred, cls, prop, keys);
    k_topk<<<BN, 1024, 0, stream>>>(keys, prop, topb);
    k_nmsmask<<<dim3(PRE / 8, BN), 256, 0, stream>>>(topb, masks);
    k_nmsreduce<<<BN, 64, 0, stream>>>(masks, topb, out);
    k_labels<<<dim3((N_ANCH + 255) / 256, BN), 256, 0, stream>>>(gt, labels, argmax_b);
    k_gtbest<<<BN * NG, 256, 0, stream>>>(gt, gt_best);
    k_gtapply<<<1, 256, 0, stream>>>(gt_best, labels);
    k_sample<<<BN, 1024, 0, stream>>>(labels, final_labels, cnt_out);
    k_loss<<<(TOTAL + 255) / 256, 256, 0, stream>>>(pred, cls, gt, final_labels, argmax_b, acc);
    k_final<<<1, 64, 0, stream>>>(acc, cnt_out, out);
}